// Round 10
// baseline (1174.951 us; speedup 1.0000x reference)
//
#include <hip/hip_runtime.h>
#include <hip/hip_cooperative_groups.h>
#include <hip/hip_bf16.h>
#include <math.h>

namespace cg = cooperative_groups;

#define N_NODES 50000
#define FDIM 64
#define BETA 0.5f
#define NEG_SLOPE 0.2f

typedef __attribute__((ext_vector_type(8))) short bf16x8;
typedef __attribute__((ext_vector_type(4))) float f32x4;

__device__ __forceinline__ unsigned short f2bf(float f) {
    unsigned u = __float_as_uint(f);
    unsigned r = (u + 0x7FFFu + ((u >> 16) & 1u)) >> 16;
    return (unsigned short)r;
}
__device__ __forceinline__ float bf2f(unsigned short s) {
    return __uint_as_float((unsigned)s << 16);
}

// ---------------------------------------------------------------------------
// Coalesced bucketed scatter (R3): chunk locally bucket-grouped in LDS, then
// flushed linearly. staged word = src | dlow<<16 (bucket in bits 24-31).
#define CHUNK 4096
__global__ __launch_bounds__(256) void scatter_pairs(
    const unsigned int* __restrict__ eiu, int* __restrict__ gCursor,
    unsigned int* __restrict__ pairs, int E, int CAP) {
    __shared__ int det;
    __shared__ unsigned int staged[CHUNK];       // 16 KB
    __shared__ unsigned short tmpd[CHUNK];       // 8 KB: low 16 bits of dst
    __shared__ int hist[256], sc[256], lbase[256], gbase[256], lcur[256];
    int t = threadIdx.x;
    if (t == 0) det = 0;
    hist[t] = 0;
    __syncthreads();
    int beg = blockIdx.x * CHUNK;
    int end = min(E, beg + CHUNK);
    int n = end - beg;
    {   // int32 vs int64 self-detection: int64 odd dwords are all zero
        int idx = beg + t;
        if (idx < E && eiu[2 * idx + 1] != 0u) atomicOr(&det, 1);
    }
    __syncthreads();
    bool is32 = det != 0;
    for (int i = beg + t; i < end; i += 256) {
        int d = is32 ? (int)eiu[E + i] : (int)eiu[2 * (size_t)(E + i)];
        tmpd[i - beg] = (unsigned short)d;
        atomicAdd(&hist[d >> 8], 1);
    }
    __syncthreads();
    sc[t] = hist[t];
    __syncthreads();
    for (int off = 1; off < 256; off <<= 1) {
        int v = (t >= off) ? sc[t - off] : 0;
        __syncthreads();
        sc[t] += v;
        __syncthreads();
    }
    int excl = sc[t] - hist[t];
    lbase[t] = excl;
    lcur[t] = excl;
    if (hist[t] > 0) gbase[t] = t * CAP + atomicAdd(&gCursor[t], hist[t]);
    __syncthreads();
    for (int i = beg + t; i < end; i += 256) {
        unsigned s = is32 ? eiu[i] : eiu[2 * (size_t)i];
        unsigned td = tmpd[i - beg];
        int b = (int)(td >> 8);
        int lp = atomicAdd(&lcur[b], 1);
        staged[lp] = s | (td << 16);
    }
    __syncthreads();
    for (int j = t; j < n; j += 256) {
        unsigned w = staged[j];
        int b = (int)(w >> 24);
        pairs[gbase[b] + (j - lbase[b])] = w;
    }
}

// One block (1024 thr) per bucket: counting sort by dst-low byte, LDS-staged
// coalesced ushort flush; also accumulates the global degree histogram
// (cnt[t] IS node (b<<8)+t's degree).
__global__ __launch_bounds__(1024) void bucket_sort(
    const unsigned int* __restrict__ pairs, const int* __restrict__ gCursor,
    int* __restrict__ offsets, unsigned short* __restrict__ srcs,
    int* __restrict__ degCnt, int N, int E, int CAP) {
    __shared__ int scb[256], cnt[256], sc[256], lcur[256], dh[256];
    __shared__ unsigned short sorted16[16384];   // 32 KB
    int b = blockIdx.x, t = threadIdx.x;
    if (t < 256) { scb[t] = gCursor[t]; dh[t] = 0; }
    __syncthreads();
    for (int off = 1; off < 256; off <<= 1) {
        int v = (t < 256 && t >= off) ? scb[t - off] : 0;
        __syncthreads();
        if (t < 256) scb[t] += v;
        __syncthreads();
    }
    int cntb = gCursor[b];
    int beg = scb[b] - cntb;
    int pbase = b * CAP;
    bool useLds = cntb <= 16384;
    if (b == 0 && t == 0) offsets[N] = E;
    if (t < 256) cnt[t] = 0;
    __syncthreads();
    for (int i = t; i < cntb; i += 1024) atomicAdd(&cnt[(pairs[pbase + i] >> 16) & 255u], 1);
    __syncthreads();
    if (t < 256) {
        sc[t] = cnt[t];
        int node = (b << 8) + t;
        if (node < N) atomicAdd(&dh[min(cnt[t], 255)], 1);   // degree histogram
    }
    __syncthreads();
    if (t < 256 && dh[t]) atomicAdd(&degCnt[t], dh[t]);
    for (int off = 1; off < 256; off <<= 1) {
        int v = (t < 256 && t >= off) ? sc[t - off] : 0;
        __syncthreads();
        if (t < 256) sc[t] += v;
        __syncthreads();
    }
    if (t < 256) {
        int excl = sc[t] - cnt[t];
        int node = (b << 8) + t;
        if (node < N) offsets[node] = beg + excl;
        lcur[t] = excl;
    }
    __syncthreads();
    if (useLds) {
        for (int i = t; i < cntb; i += 1024) {
            unsigned p = pairs[pbase + i];
            int lp = atomicAdd(&lcur[(p >> 16) & 255u], 1);
            sorted16[lp] = (unsigned short)(p & 0xFFFFu);
        }
        __syncthreads();
        for (int j = t; j < cntb; j += 1024) srcs[beg + j] = sorted16[j];
    } else {
        for (int i = t; i < cntb; i += 1024) {
            unsigned p = pairs[pbase + i];
            int lp = atomicAdd(&lcur[(p >> 16) & 255u], 1);
            srcs[beg + lp] = (unsigned short)(p & 0xFFFFu);
        }
    }
}

// ---------------------------------------------------------------------------
// Degree counting-sort scatter with the scan folded in (per-block redundant
// 256-bin scan + block-aggregated reservation on a relative cursor).
#define DCHUNK 2048
__global__ __launch_bounds__(256) void deg_scatter(
    const int* __restrict__ offsets, const int* __restrict__ degHist,
    int* __restrict__ cursorRel, int* __restrict__ perm, int N) {
    __shared__ int scanB[256], lh[256], lbase[256], lcur[256];
    int t = threadIdx.x;
    int c = degHist[t];
    scanB[t] = c;
    __syncthreads();
    for (int off = 1; off < 256; off <<= 1) {
        int v = (t >= off) ? scanB[t - off] : 0;
        __syncthreads();
        scanB[t] += v;
        __syncthreads();
    }
    int base0 = scanB[t] - c;   // exclusive base for degree bin t
    lh[t] = 0;
    lcur[t] = 0;
    __syncthreads();
    int beg = blockIdx.x * DCHUNK;
    int end = min(N, beg + DCHUNK);
    for (int i = beg + t; i < end; i += 256) {
        int d = min(offsets[i + 1] - offsets[i], 255);
        atomicAdd(&lh[d], 1);
    }
    __syncthreads();
    if (lh[t] > 0) lbase[t] = base0 + atomicAdd(&cursorRel[t], lh[t]);
    __syncthreads();
    for (int i = beg + t; i < end; i += 256) {
        int d = min(offsets[i + 1] - offsets[i], 255);
        int r = atomicAdd(&lcur[d], 1);
        perm[lbase[d] + r] = i;
    }
}

// ---------------------------------------------------------------------------
// Prep: transpose W and fc_w into bf16 hi/lo, WT[f*64+k] = split(W[k*64+f]).
__global__ __launch_bounds__(256) void prep_weights(
    const float* __restrict__ W, const float* __restrict__ fcw,
    unsigned short* __restrict__ WTh, unsigned short* __restrict__ WTl,
    unsigned short* __restrict__ FTh, unsigned short* __restrict__ FTl) {
    for (int idx = blockIdx.x * 256 + threadIdx.x; idx < 4096; idx += gridDim.x * 256) {
        int k = idx >> 6, f = idx & 63;
        float w = W[idx];
        unsigned short hi = f2bf(w);
        WTh[f * 64 + k] = hi;
        WTl[f * 64 + k] = f2bf(w - bf2f(hi));
        float w2 = fcw[idx];
        unsigned short hi2 = f2bf(w2);
        FTh[f * 64 + k] = hi2;
        FTl[f * 64 + k] = f2bf(w2 - bf2f(hi2));
    }
}

// ---------------------------------------------------------------------------
// Shared device phase bodies (used by both the fused cooperative kernel and
// the separate-kernel fallback path).

__device__ void load_w_lds(
    unsigned short* WThs, unsigned short* WTls,
    const unsigned short* __restrict__ WTh, const unsigned short* __restrict__ WTl) {
    int tid = threadIdx.x;
    int row = tid >> 2;            // 0..63
    int ch = (tid & 3) * 16;       // shorts
    uint4 h0 = ((const uint4*)(WTh + row * 64 + ch))[0];
    uint4 h1 = ((const uint4*)(WTh + row * 64 + ch))[1];
    uint4 l0 = ((const uint4*)(WTl + row * 64 + ch))[0];
    uint4 l1 = ((const uint4*)(WTl + row * 64 + ch))[1];
    *((uint4*)(WThs + row * 72 + ch)) = h0;
    *((uint4*)(WThs + row * 72 + ch + 8)) = h1;
    *((uint4*)(WTls + row * 72 + ch)) = l0;
    *((uint4*)(WTls + row * 72 + ch + 8)) = l1;
    __syncthreads();
}

__device__ void transform_phase(
    const float* __restrict__ xin,
    const unsigned short* __restrict__ WThs, const unsigned short* __restrict__ WTls,
    const float* __restrict__ a_src, const float* __restrict__ a_dst,  // nullable
    const float* __restrict__ bias,                                    // nullable
    unsigned short* __restrict__ hb,  // nullable
    float* __restrict__ fout,         // nullable
    float* __restrict__ as_, float* __restrict__ ad_, int N) {
    int tid = threadIdx.x;
    int wid = tid >> 6;
    int lane = tid & 63;
    int col = lane & 15;
    int quad = lane >> 4;
    int chunks = (N + 63) >> 6;

    for (int cb = blockIdx.x; cb < chunks; cb += gridDim.x) {
        int mbase = cb * 64 + wid * 16;

        bf16x8 Ah[2], Al[2];
        int arow = mbase + col;
        const float* xr = xin + (size_t)(arow < N ? arow : 0) * FDIM + quad * 8;
#pragma unroll
        for (int ks = 0; ks < 2; ks++) {
            float4 xa = *(const float4*)(xr + ks * 32);
            float4 xb = *(const float4*)(xr + ks * 32 + 4);
            float xv[8] = {xa.x, xa.y, xa.z, xa.w, xb.x, xb.y, xb.z, xb.w};
#pragma unroll
            for (int e = 0; e < 8; e++) {
                unsigned short hi = f2bf(xv[e]);
                Ah[ks][e] = (short)hi;
                Al[ks][e] = (short)f2bf(xv[e] - bf2f(hi));
            }
        }

        f32x4 acc[4];
#pragma unroll
        for (int ft = 0; ft < 4; ft++) acc[ft] = (f32x4){0.f, 0.f, 0.f, 0.f};
#pragma unroll
        for (int ft = 0; ft < 4; ft++) {
            int f = ft * 16 + col;
#pragma unroll
            for (int ks = 0; ks < 2; ks++) {
                int off = f * 72 + ks * 32 + quad * 8;
                bf16x8 Bh = *(const bf16x8*)(WThs + off);
                bf16x8 Bl = *(const bf16x8*)(WTls + off);
                acc[ft] = __builtin_amdgcn_mfma_f32_16x16x32_bf16(Ah[ks], Bh, acc[ft], 0, 0, 0);
                acc[ft] = __builtin_amdgcn_mfma_f32_16x16x32_bf16(Ah[ks], Bl, acc[ft], 0, 0, 0);
                acc[ft] = __builtin_amdgcn_mfma_f32_16x16x32_bf16(Al[ks], Bh, acc[ft], 0, 0, 0);
            }
        }

        if (fout) {
#pragma unroll
            for (int ft = 0; ft < 4; ft++) {
                int f = ft * 16 + col;
                float bv = bias ? bias[f] : 0.f;
#pragma unroll
                for (int r = 0; r < 4; r++) {
                    int node = mbase + quad * 4 + r;
                    if (node < N) fout[(size_t)node * FDIM + f] = acc[ft][r] + bv;
                }
            }
        }
        if (hb) {
#pragma unroll
            for (int ft = 0; ft < 4; ft++) {
                int f = ft * 16 + col;
#pragma unroll
                for (int r = 0; r < 4; r++) {
                    int node = mbase + quad * 4 + r;
                    if (node < N) hb[(size_t)node * FDIM + f] = f2bf(acc[ft][r]);
                }
            }
        }
        if (as_) {
            float asv[4], adv[4];
#pragma unroll
            for (int ft = 0; ft < 4; ft++) {
                asv[ft] = a_src[ft * 16 + col];
                adv[ft] = a_dst[ft * 16 + col];
            }
#pragma unroll
            for (int r = 0; r < 4; r++) {
                float pa = 0.f, pd = 0.f;
#pragma unroll
                for (int ft = 0; ft < 4; ft++) {
                    pa = fmaf(acc[ft][r], asv[ft], pa);
                    pd = fmaf(acc[ft][r], adv[ft], pd);
                }
#pragma unroll
                for (int off = 1; off <= 8; off <<= 1) {
                    pa += __shfl_xor(pa, off, 64);
                    pd += __shfl_xor(pd, off, 64);
                }
                int node = mbase + quad * 4 + r;
                if (col == 0 && node < N) { as_[node] = pa; ad_[node] = pd; }
            }
        }
    }
}

__device__ __forceinline__ void fma8(float* acc, float ex, const uint4& hv) {
    acc[0] = fmaf(ex, __uint_as_float(hv.x << 16), acc[0]);
    acc[1] = fmaf(ex, __uint_as_float(hv.x & 0xFFFF0000u), acc[1]);
    acc[2] = fmaf(ex, __uint_as_float(hv.y << 16), acc[2]);
    acc[3] = fmaf(ex, __uint_as_float(hv.y & 0xFFFF0000u), acc[3]);
    acc[4] = fmaf(ex, __uint_as_float(hv.z << 16), acc[4]);
    acc[5] = fmaf(ex, __uint_as_float(hv.z & 0xFFFF0000u), acc[5]);
    acc[6] = fmaf(ex, __uint_as_float(hv.w << 16), acc[6]);
    acc[7] = fmaf(ex, __uint_as_float(hv.w & 0xFFFF0000u), acc[7]);
}

// 8 nodes/wave, 4-deep + src prefetch (best-known R5/R7 config), grid-stride.
__device__ void gather_phase(
    const unsigned short* __restrict__ hb,
    const float* __restrict__ as_, const float* __restrict__ ad_,
    const int* __restrict__ offsets, const unsigned short* __restrict__ srcs,
    const int* __restrict__ perm,
    const float* __restrict__ bvec, const float* __restrict__ x0,
    float* __restrict__ xout, int N) {
    int lane = threadIdx.x & 63;
    int g = lane >> 3;       // node slot 0..7
    int q = lane & 7;        // feature octet 0..7
    int wv0 = (blockIdx.x * blockDim.x + threadIdx.x) >> 6;
    int totw = (gridDim.x * blockDim.x) >> 6;
    int ngroups = (N + 7) >> 3;
    const unsigned short* hq = hb + (q << 3);

#define LRELU_EXP(E_) __expf((E_) > 0.f ? (E_) : NEG_SLOPE * (E_))
    for (int wid = wv0; wid < ngroups; wid += totw) {
        int ni = wid * 8 + g;
        bool active = ni < N;
        int node = active ? perm[ni] : 0;
        int beg = active ? offsets[node] : 0;
        int end = active ? offsets[node + 1] : 0;
        int deg = end - beg;
        float adv = active ? ad_[node] : 0.f;
        int mx = deg;
        mx = max(mx, __shfl_xor(mx, 8, 64));
        mx = max(mx, __shfl_xor(mx, 16, 64));
        mx = max(mx, __shfl_xor(mx, 32, 64));

        float acc[8];
#pragma unroll
        for (int k = 0; k < 8; k++) acc[k] = 0.f;
        float denom = 0.f;

        int p0 = (int)srcs[(0 < deg) ? beg + 0 : 0];
        int p1 = (int)srcs[(1 < deg) ? beg + 1 : 0];
        int p2 = (int)srcs[(2 < deg) ? beg + 2 : 0];
        int p3 = (int)srcs[(3 < deg) ? beg + 3 : 0];

        for (int st = 0; st < mx; st += 4) {
            int ns = st + 4;
            int n0 = (int)srcs[(ns + 0 < deg) ? beg + ns + 0 : 0];
            int n1 = (int)srcs[(ns + 1 < deg) ? beg + ns + 1 : 0];
            int n2 = (int)srcs[(ns + 2 < deg) ? beg + ns + 2 : 0];
            int n3 = (int)srcs[(ns + 3 < deg) ? beg + ns + 3 : 0];
            uint4 hv0 = *(const uint4*)(hq + ((size_t)p0 << 6));
            uint4 hv1 = *(const uint4*)(hq + ((size_t)p1 << 6));
            uint4 hv2 = *(const uint4*)(hq + ((size_t)p2 << 6));
            uint4 hv3 = *(const uint4*)(hq + ((size_t)p3 << 6));
            float e0 = as_[p0] + adv;
            float e1 = as_[p1] + adv;
            float e2 = as_[p2] + adv;
            float e3 = as_[p3] + adv;
            float ex0 = (st + 0 < deg) ? LRELU_EXP(e0) : 0.f;
            float ex1 = (st + 1 < deg) ? LRELU_EXP(e1) : 0.f;
            float ex2 = (st + 2 < deg) ? LRELU_EXP(e2) : 0.f;
            float ex3 = (st + 3 < deg) ? LRELU_EXP(e3) : 0.f;
            denom += (ex0 + ex1) + (ex2 + ex3);
            fma8(acc, ex0, hv0);
            fma8(acc, ex1, hv1);
            fma8(acc, ex2, hv2);
            fma8(acc, ex3, hv3);
            p0 = n0; p1 = n1; p2 = n2; p3 = n3;
        }

        if (active) {
            float inv = denom > 0.f ? 1.f / denom : 0.f;
            int fb = q * 8;
            f32x4 b0 = *(const f32x4*)(bvec + fb);
            f32x4 b1 = *(const f32x4*)(bvec + fb + 4);
            const float* x0r = x0 + (size_t)node * FDIM + fb;
            f32x4 x0a = *(const f32x4*)(x0r);
            f32x4 x0b = *(const f32x4*)(x0r + 4);
            f32x4 o0, o1;
            o0.x = BETA * (acc[0] * inv + b0.x) + (1.f - BETA) * x0a.x;
            o0.y = BETA * (acc[1] * inv + b0.y) + (1.f - BETA) * x0a.y;
            o0.z = BETA * (acc[2] * inv + b0.z) + (1.f - BETA) * x0a.z;
            o0.w = BETA * (acc[3] * inv + b0.w) + (1.f - BETA) * x0a.w;
            o1.x = BETA * (acc[4] * inv + b1.x) + (1.f - BETA) * x0b.x;
            o1.y = BETA * (acc[5] * inv + b1.y) + (1.f - BETA) * x0b.y;
            o1.z = BETA * (acc[6] * inv + b1.z) + (1.f - BETA) * x0b.z;
            o1.w = BETA * (acc[7] * inv + b1.w) + (1.f - BETA) * x0b.w;
            float* xr = xout + (size_t)node * FDIM + fb;
            *(f32x4*)(xr) = o0;
            *(f32x4*)(xr + 4) = o1;
        }
    }
#undef LRELU_EXP
}

// ---------------------------------------------------------------------------
// Fused cooperative layer chain: 7 phases, grid.sync between. Explicit
// __threadfence() around each sync as cross-XCD fencing insurance (G16).
__global__ __launch_bounds__(256, 4) void fused_layers(
    const float* __restrict__ x,
    const unsigned short* __restrict__ WTh, const unsigned short* __restrict__ WTl,
    const unsigned short* __restrict__ FTh, const unsigned short* __restrict__ FTl,
    const float* __restrict__ a_src, const float* __restrict__ a_dst,
    const float* __restrict__ bvec, const float* __restrict__ fc_b,
    const int* __restrict__ offsets, const unsigned short* __restrict__ srcs,
    const int* __restrict__ perm,
    float* __restrict__ as_, float* __restrict__ ad_,
    unsigned short* __restrict__ hbuf, float* __restrict__ xbuf,
    float* __restrict__ out, float* __restrict__ x3, int N) {
    cg::grid_group grid = cg::this_grid();
    __shared__ __align__(16) unsigned short WThs[64 * 72];
    __shared__ __align__(16) unsigned short WTls[64 * 72];

#define GSYNC() { __threadfence(); grid.sync(); __threadfence(); }
    load_w_lds(WThs, WTls, WTh, WTl);
    // layer 1
    transform_phase(x, WThs, WTls, a_src, a_dst, nullptr, hbuf, nullptr, as_, ad_, N);
    GSYNC();
    gather_phase(hbuf, as_, ad_, offsets, srcs, perm, bvec, x, xbuf, N);
    GSYNC();
    // layer 2
    transform_phase(xbuf, WThs, WTls, a_src, a_dst, nullptr, hbuf, nullptr, as_, ad_, N);
    GSYNC();
    gather_phase(hbuf, as_, ad_, offsets, srcs, perm, bvec, x, xbuf, N);
    GSYNC();
    // layer 3
    transform_phase(xbuf, WThs, WTls, a_src, a_dst, nullptr, hbuf, nullptr, as_, ad_, N);
    GSYNC();
    gather_phase(hbuf, as_, ad_, offsets, srcs, perm, bvec, x, x3, N);
    GSYNC();
    // final fc: out = x3 @ fc_w + fc_b  (reload LDS with FC weights)
    load_w_lds(WThs, WTls, FTh, FTl);
    transform_phase(x3, WThs, WTls, nullptr, nullptr, fc_b, nullptr, out,
                    nullptr, nullptr, N);
#undef GSYNC
}

// ---------------------------------------------------------------------------
// Fallback wrappers (separate launches; R5-equivalent proven path).
__global__ __launch_bounds__(256, 4) void transform_k(
    const float* __restrict__ xin,
    const unsigned short* __restrict__ WTh, const unsigned short* __restrict__ WTl,
    const float* __restrict__ a_src, const float* __restrict__ a_dst,
    const float* __restrict__ bias,
    unsigned short* __restrict__ hb, float* __restrict__ fout,
    float* __restrict__ as_, float* __restrict__ ad_, int N) {
    __shared__ __align__(16) unsigned short WThs[64 * 72];
    __shared__ __align__(16) unsigned short WTls[64 * 72];
    load_w_lds(WThs, WTls, WTh, WTl);
    transform_phase(xin, WThs, WTls, a_src, a_dst, bias, hb, fout, as_, ad_, N);
}

__global__ __launch_bounds__(256) void gather_k(
    const unsigned short* __restrict__ hb,
    const float* __restrict__ as_, const float* __restrict__ ad_,
    const int* __restrict__ offsets, const unsigned short* __restrict__ srcs,
    const int* __restrict__ perm,
    const float* __restrict__ bvec, const float* __restrict__ x0,
    float* __restrict__ xout, int N) {
    gather_phase(hb, as_, ad_, offsets, srcs, perm, bvec, x0, xout, N);
}

// ---------------------------------------------------------------------------
extern "C" void kernel_launch(void* const* d_in, const int* in_sizes, int n_in,
                              void* d_out, int out_size, void* d_ws, size_t ws_size,
                              hipStream_t stream) {
    const int N = N_NODES;
    const int E = in_sizes[1] / 2;
    const int NB = (N + 255) >> 8;   // 196 buckets
    const int CAP = (((E / N) * 256) * 2 + 1023) & ~1023;   // 16384 here

    const float* x     = (const float*)d_in[0];
    const void*  ei    = d_in[1];
    const float* W     = (const float*)d_in[2];
    const float* a_src = (const float*)d_in[3];
    const float* a_dst = (const float*)d_in[4];
    const float* bvec  = (const float*)d_in[5];
    const float* fc_w  = (const float*)d_in[6];
    const float* fc_b  = (const float*)d_in[7];

    float* out = (float*)d_out;                 // [N, F]
    float* x3  = out + (size_t)N * FDIM;        // [N, F] (second output = h)

    char* p = (char*)d_ws;
    auto alloc = [&](size_t bytes) -> void* {
        void* r = (void*)p;
        p += (bytes + 255) & ~(size_t)255;
        return r;
    };
    int*            gCursor  = (int*)alloc(768 * 4);   // gCursor + degCnt + cursorRel
    unsigned int*   pairs    = (unsigned int*)alloc((size_t)256 * CAP * 4);
    unsigned short* srcs     = (unsigned short*)alloc((size_t)E * 2);
    int*            offsets  = (int*)alloc((size_t)(N + 1) * 4);
    int*            perm     = (int*)alloc((size_t)N * 4);
    float*          as_      = (float*)alloc((size_t)N * 4);
    float*          ad_      = (float*)alloc((size_t)N * 4);
    unsigned short* hbuf     = (unsigned short*)alloc((size_t)N * FDIM * 2);
    float*          xbuf     = (float*)alloc((size_t)N * FDIM * 4);
    unsigned short* WTh      = (unsigned short*)alloc(4096 * 2);
    unsigned short* WTl      = (unsigned short*)alloc(4096 * 2);
    unsigned short* FTh      = (unsigned short*)alloc(4096 * 2);
    unsigned short* FTl      = (unsigned short*)alloc(4096 * 2);
    int* degCnt    = gCursor + 256;
    int* cursorRel = gCursor + 512;

    hipMemsetAsync(gCursor, 0, 768 * 4, stream);

    prep_weights<<<16, 256, 0, stream>>>(W, fc_w, WTh, WTl, FTh, FTl);

    scatter_pairs<<<(E + CHUNK - 1) / CHUNK, 256, 0, stream>>>(
        (const unsigned int*)ei, gCursor, pairs, E, CAP);
    bucket_sort<<<NB, 1024, 0, stream>>>(pairs, gCursor, offsets, srcs, degCnt, N, E, CAP);
    deg_scatter<<<(N + DCHUNK - 1) / DCHUNK, 256, 0, stream>>>(
        offsets, degCnt, cursorRel, perm, N);

    // -- fused cooperative chain, sized by MEASURED occupancy (R9 failure:
    //    assumed 4 blocks/CU, launch silently rejected). Fallback on any error.
    static int maxB = -2;   // -2 = not yet queried
    if (maxB == -2) {
        int mb = 0;
        hipError_t qe = hipOccupancyMaxActiveBlocksPerMultiprocessor(
            &mb, fused_layers, 256, 0);
        maxB = (qe == hipSuccess) ? mb : 0;
    }
    bool coop_done = false;
    if (maxB > 0) {
        int fgrid = maxB * 256;              // 256 CUs
        if (fgrid > 1568) fgrid = 1568;      // enough for 1 node-group/wave
        int nval = N;
        void* args[19];
        args[0] = (void*)&x;    args[1] = (void*)&WTh;  args[2] = (void*)&WTl;
        args[3] = (void*)&FTh;  args[4] = (void*)&FTl;  args[5] = (void*)&a_src;
        args[6] = (void*)&a_dst; args[7] = (void*)&bvec; args[8] = (void*)&fc_b;
        args[9] = (void*)&offsets; args[10] = (void*)&srcs; args[11] = (void*)&perm;
        args[12] = (void*)&as_; args[13] = (void*)&ad_;  args[14] = (void*)&hbuf;
        args[15] = (void*)&xbuf; args[16] = (void*)&out; args[17] = (void*)&x3;
        args[18] = (void*)&nval;
        hipError_t le = hipLaunchCooperativeKernel(
            (void*)fused_layers, dim3(fgrid), dim3(256), args, 0, stream);
        coop_done = (le == hipSuccess);
    }

    if (!coop_done) {
        // proven separate-kernel path (R5-equivalent)
        int tgrid = (N + 63) / 64;
        int gwaves = (N + 7) / 8;
        int ggrid = (gwaves + 3) / 4;
        transform_k<<<tgrid, 256, 0, stream>>>(x, WTh, WTl, a_src, a_dst, nullptr,
                                               hbuf, nullptr, as_, ad_, N);
        gather_k<<<ggrid, 256, 0, stream>>>(hbuf, as_, ad_, offsets, srcs, perm,
                                            bvec, x, xbuf, N);
        transform_k<<<tgrid, 256, 0, stream>>>(xbuf, WTh, WTl, a_src, a_dst, nullptr,
                                               hbuf, nullptr, as_, ad_, N);
        gather_k<<<ggrid, 256, 0, stream>>>(hbuf, as_, ad_, offsets, srcs, perm,
                                            bvec, x, xbuf, N);
        transform_k<<<tgrid, 256, 0, stream>>>(xbuf, WTh, WTl, a_src, a_dst, nullptr,
                                               hbuf, nullptr, as_, ad_, N);
        gather_k<<<ggrid, 256, 0, stream>>>(hbuf, as_, ad_, offsets, srcs, perm,
                                            bvec, x, x3, N);
        transform_k<<<tgrid, 256, 0, stream>>>(x3, FTh, FTl, nullptr, nullptr, fc_b,
                                               nullptr, out, nullptr, nullptr, N);
    }
}

// Round 11
// 250.918 us; speedup vs baseline: 4.6826x; 4.6826x over previous
//
#include <hip/hip_runtime.h>
#include <hip/hip_bf16.h>
#include <math.h>

#define N_NODES 50000
#define FDIM 64
#define BETA 0.5f
#define NEG_SLOPE 0.2f

typedef __attribute__((ext_vector_type(8))) short bf16x8;
typedef __attribute__((ext_vector_type(4))) float f32x4;

__device__ __forceinline__ unsigned short f2bf(float f) {
    unsigned u = __float_as_uint(f);
    unsigned r = (u + 0x7FFFu + ((u >> 16) & 1u)) >> 16;
    return (unsigned short)r;
}
__device__ __forceinline__ float bf2f(unsigned short s) {
    return __uint_as_float((unsigned)s << 16);
}

// ---------------------------------------------------------------------------
// Coalesced bucketed scatter (R3) with prep_weights FOLDED IN: the last block
// of the grid transposes W/fc_w into bf16 hi/lo instead of scattering edges
// (independent work; saves one kernel launch + gap). staged word =
// src | dlow<<16 (bucket in bits 24-31).
#define CHUNK 4096
__global__ __launch_bounds__(256) void scatter_pairs(
    const unsigned int* __restrict__ eiu, int* __restrict__ gCursor,
    unsigned int* __restrict__ pairs, int E, int CAP, int nChunks,
    const float* __restrict__ W, const float* __restrict__ fcw,
    unsigned short* __restrict__ WTh, unsigned short* __restrict__ WTl,
    unsigned short* __restrict__ FTh, unsigned short* __restrict__ FTl) {
    int t = threadIdx.x;
    if (blockIdx.x >= nChunks) {          // weight-prep block
        for (int idx = t; idx < 4096; idx += 256) {
            int k = idx >> 6, f = idx & 63;
            float w = W[idx];
            unsigned short hi = f2bf(w);
            WTh[f * 64 + k] = hi;
            WTl[f * 64 + k] = f2bf(w - bf2f(hi));
            float w2 = fcw[idx];
            unsigned short hi2 = f2bf(w2);
            FTh[f * 64 + k] = hi2;
            FTl[f * 64 + k] = f2bf(w2 - bf2f(hi2));
        }
        return;
    }
    __shared__ int det;
    __shared__ unsigned int staged[CHUNK];       // 16 KB
    __shared__ unsigned short tmpd[CHUNK];       // 8 KB: low 16 bits of dst
    __shared__ int hist[256], sc[256], lbase[256], gbase[256], lcur[256];
    if (t == 0) det = 0;
    hist[t] = 0;
    __syncthreads();
    int beg = blockIdx.x * CHUNK;
    int end = min(E, beg + CHUNK);
    int n = end - beg;
    {   // int32 vs int64 self-detection: int64 odd dwords are all zero
        int idx = beg + t;
        if (idx < E && eiu[2 * idx + 1] != 0u) atomicOr(&det, 1);
    }
    __syncthreads();
    bool is32 = det != 0;
    for (int i = beg + t; i < end; i += 256) {
        int d = is32 ? (int)eiu[E + i] : (int)eiu[2 * (size_t)(E + i)];
        tmpd[i - beg] = (unsigned short)d;
        atomicAdd(&hist[d >> 8], 1);
    }
    __syncthreads();
    sc[t] = hist[t];
    __syncthreads();
    for (int off = 1; off < 256; off <<= 1) {
        int v = (t >= off) ? sc[t - off] : 0;
        __syncthreads();
        sc[t] += v;
        __syncthreads();
    }
    int excl = sc[t] - hist[t];
    lbase[t] = excl;
    lcur[t] = excl;
    if (hist[t] > 0) gbase[t] = t * CAP + atomicAdd(&gCursor[t], hist[t]);
    __syncthreads();
    for (int i = beg + t; i < end; i += 256) {
        unsigned s = is32 ? eiu[i] : eiu[2 * (size_t)i];
        unsigned td = tmpd[i - beg];
        int b = (int)(td >> 8);
        int lp = atomicAdd(&lcur[b], 1);
        staged[lp] = s | (td << 16);
    }
    __syncthreads();
    for (int j = t; j < n; j += 256) {
        unsigned w = staged[j];
        int b = (int)(w >> 24);
        pairs[gbase[b] + (j - lbase[b])] = w;
    }
}

// One block (1024 thr) per bucket: counting sort by dst-low byte, LDS-staged
// coalesced ushort flush; also accumulates the global degree histogram
// (cnt[t] IS node (b<<8)+t's degree).
__global__ __launch_bounds__(1024) void bucket_sort(
    const unsigned int* __restrict__ pairs, const int* __restrict__ gCursor,
    int* __restrict__ offsets, unsigned short* __restrict__ srcs,
    int* __restrict__ degCnt, int N, int E, int CAP) {
    __shared__ int scb[256], cnt[256], sc[256], lcur[256], dh[256];
    __shared__ unsigned short sorted16[16384];   // 32 KB
    int b = blockIdx.x, t = threadIdx.x;
    if (t < 256) { scb[t] = gCursor[t]; dh[t] = 0; }
    __syncthreads();
    for (int off = 1; off < 256; off <<= 1) {
        int v = (t < 256 && t >= off) ? scb[t - off] : 0;
        __syncthreads();
        if (t < 256) scb[t] += v;
        __syncthreads();
    }
    int cntb = gCursor[b];
    int beg = scb[b] - cntb;
    int pbase = b * CAP;
    bool useLds = cntb <= 16384;
    if (b == 0 && t == 0) offsets[N] = E;
    if (t < 256) cnt[t] = 0;
    __syncthreads();
    for (int i = t; i < cntb; i += 1024) atomicAdd(&cnt[(pairs[pbase + i] >> 16) & 255u], 1);
    __syncthreads();
    if (t < 256) {
        sc[t] = cnt[t];
        int node = (b << 8) + t;
        if (node < N) atomicAdd(&dh[min(cnt[t], 255)], 1);   // degree histogram
    }
    __syncthreads();
    if (t < 256 && dh[t]) atomicAdd(&degCnt[t], dh[t]);
    for (int off = 1; off < 256; off <<= 1) {
        int v = (t < 256 && t >= off) ? sc[t - off] : 0;
        __syncthreads();
        if (t < 256) sc[t] += v;
        __syncthreads();
    }
    if (t < 256) {
        int excl = sc[t] - cnt[t];
        int node = (b << 8) + t;
        if (node < N) offsets[node] = beg + excl;
        lcur[t] = excl;
    }
    __syncthreads();
    if (useLds) {
        for (int i = t; i < cntb; i += 1024) {
            unsigned p = pairs[pbase + i];
            int lp = atomicAdd(&lcur[(p >> 16) & 255u], 1);
            sorted16[lp] = (unsigned short)(p & 0xFFFFu);
        }
        __syncthreads();
        for (int j = t; j < cntb; j += 1024) srcs[beg + j] = sorted16[j];
    } else {
        for (int i = t; i < cntb; i += 1024) {
            unsigned p = pairs[pbase + i];
            int lp = atomicAdd(&lcur[(p >> 16) & 255u], 1);
            srcs[beg + lp] = (unsigned short)(p & 0xFFFFu);
        }
    }
}

// ---------------------------------------------------------------------------
// Degree counting-sort scatter with the scan folded in (per-block redundant
// 256-bin scan + block-aggregated reservation on a relative cursor).
#define DCHUNK 2048
__global__ __launch_bounds__(256) void deg_scatter(
    const int* __restrict__ offsets, const int* __restrict__ degHist,
    int* __restrict__ cursorRel, int* __restrict__ perm, int N) {
    __shared__ int scanB[256], lh[256], lbase[256], lcur[256];
    int t = threadIdx.x;
    int c = degHist[t];
    scanB[t] = c;
    __syncthreads();
    for (int off = 1; off < 256; off <<= 1) {
        int v = (t >= off) ? scanB[t - off] : 0;
        __syncthreads();
        scanB[t] += v;
        __syncthreads();
    }
    int base0 = scanB[t] - c;   // exclusive base for degree bin t
    lh[t] = 0;
    lcur[t] = 0;
    __syncthreads();
    int beg = blockIdx.x * DCHUNK;
    int end = min(N, beg + DCHUNK);
    for (int i = beg + t; i < end; i += 256) {
        int d = min(offsets[i + 1] - offsets[i], 255);
        atomicAdd(&lh[d], 1);
    }
    __syncthreads();
    if (lh[t] > 0) lbase[t] = base0 + atomicAdd(&cursorRel[t], lh[t]);
    __syncthreads();
    for (int i = beg + t; i < end; i += 256) {
        int d = min(offsets[i + 1] - offsets[i], 255);
        int r = atomicAdd(&lcur[d], 1);
        perm[lbase[d] + r] = i;
    }
}

// ---------------------------------------------------------------------------
// Split-bf16 MFMA transform: h = x@W (fp32-accurate via xh*Wh + xh*Wl + xl*Wh).
__global__ __launch_bounds__(256, 4) void transform_k(
    const float* __restrict__ xin,
    const unsigned short* __restrict__ WTh, const unsigned short* __restrict__ WTl,
    const float* __restrict__ a_src, const float* __restrict__ a_dst,  // nullable
    const float* __restrict__ bias,                                    // nullable
    unsigned short* __restrict__ hb,  // nullable
    float* __restrict__ fout,         // nullable
    float* __restrict__ as_, float* __restrict__ ad_, int N) {
    __shared__ __align__(16) unsigned short WThs[64 * 72];
    __shared__ __align__(16) unsigned short WTls[64 * 72];
    int tid = threadIdx.x;
    {
        int row = tid >> 2;            // 0..63
        int ch = (tid & 3) * 16;       // shorts
        uint4 h0 = ((const uint4*)(WTh + row * 64 + ch))[0];
        uint4 h1 = ((const uint4*)(WTh + row * 64 + ch))[1];
        uint4 l0 = ((const uint4*)(WTl + row * 64 + ch))[0];
        uint4 l1 = ((const uint4*)(WTl + row * 64 + ch))[1];
        *((uint4*)(WThs + row * 72 + ch)) = h0;
        *((uint4*)(WThs + row * 72 + ch + 8)) = h1;
        *((uint4*)(WTls + row * 72 + ch)) = l0;
        *((uint4*)(WTls + row * 72 + ch + 8)) = l1;
    }

    int wid = tid >> 6;
    int lane = tid & 63;
    int col = lane & 15;
    int quad = lane >> 4;
    int mbase = blockIdx.x * 64 + wid * 16;

    bf16x8 Ah[2], Al[2];
    int arow = mbase + col;
    const float* xr = xin + (size_t)(arow < N ? arow : 0) * FDIM + quad * 8;
#pragma unroll
    for (int ks = 0; ks < 2; ks++) {
        float4 xa = *(const float4*)(xr + ks * 32);
        float4 xb = *(const float4*)(xr + ks * 32 + 4);
        float xv[8] = {xa.x, xa.y, xa.z, xa.w, xb.x, xb.y, xb.z, xb.w};
#pragma unroll
        for (int e = 0; e < 8; e++) {
            unsigned short hi = f2bf(xv[e]);
            Ah[ks][e] = (short)hi;
            Al[ks][e] = (short)f2bf(xv[e] - bf2f(hi));
        }
    }
    __syncthreads();

    f32x4 acc[4];
#pragma unroll
    for (int ft = 0; ft < 4; ft++) acc[ft] = (f32x4){0.f, 0.f, 0.f, 0.f};

#pragma unroll
    for (int ft = 0; ft < 4; ft++) {
        int f = ft * 16 + col;
#pragma unroll
        for (int ks = 0; ks < 2; ks++) {
            int off = f * 72 + ks * 32 + quad * 8;
            bf16x8 Bh = *(const bf16x8*)(WThs + off);
            bf16x8 Bl = *(const bf16x8*)(WTls + off);
            acc[ft] = __builtin_amdgcn_mfma_f32_16x16x32_bf16(Ah[ks], Bh, acc[ft], 0, 0, 0);
            acc[ft] = __builtin_amdgcn_mfma_f32_16x16x32_bf16(Ah[ks], Bl, acc[ft], 0, 0, 0);
            acc[ft] = __builtin_amdgcn_mfma_f32_16x16x32_bf16(Al[ks], Bh, acc[ft], 0, 0, 0);
        }
    }

    if (fout) {
#pragma unroll
        for (int ft = 0; ft < 4; ft++) {
            int f = ft * 16 + col;
            float bv = bias ? bias[f] : 0.f;
#pragma unroll
            for (int r = 0; r < 4; r++) {
                int node = mbase + quad * 4 + r;
                if (node < N) fout[(size_t)node * FDIM + f] = acc[ft][r] + bv;
            }
        }
    }
    if (hb) {
#pragma unroll
        for (int ft = 0; ft < 4; ft++) {
            int f = ft * 16 + col;
#pragma unroll
            for (int r = 0; r < 4; r++) {
                int node = mbase + quad * 4 + r;
                if (node < N) hb[(size_t)node * FDIM + f] = f2bf(acc[ft][r]);
            }
        }
    }
    if (as_) {
        float asv[4], adv[4];
#pragma unroll
        for (int ft = 0; ft < 4; ft++) {
            asv[ft] = a_src[ft * 16 + col];
            adv[ft] = a_dst[ft * 16 + col];
        }
#pragma unroll
        for (int r = 0; r < 4; r++) {
            float pa = 0.f, pd = 0.f;
#pragma unroll
            for (int ft = 0; ft < 4; ft++) {
                pa = fmaf(acc[ft][r], asv[ft], pa);
                pd = fmaf(acc[ft][r], adv[ft], pd);
            }
#pragma unroll
            for (int off = 1; off <= 8; off <<= 1) {
                pa += __shfl_xor(pa, off, 64);
                pd += __shfl_xor(pd, off, 64);
            }
            int node = mbase + quad * 4 + r;
            if (col == 0 && node < N) { as_[node] = pa; ad_[node] = pd; }
        }
    }
}

// ---------------------------------------------------------------------------
// Gather, 8 NODES PER WAVE, 4-deep + src-index prefetch (best-known config:
// R5 body + R7 prefetch, no nt-hints, forward order). Lane group g (8 lanes)
// owns node perm[wid*8+g]; lane q owns feature octet q. No cross-lane
// reduction, no tails (predicated uniform loop over group-max degree;
// degree-sorted perm makes max~mean~32 = 8 iters).
__device__ __forceinline__ void fma8(float* acc, float ex, const uint4& hv) {
    acc[0] = fmaf(ex, __uint_as_float(hv.x << 16), acc[0]);
    acc[1] = fmaf(ex, __uint_as_float(hv.x & 0xFFFF0000u), acc[1]);
    acc[2] = fmaf(ex, __uint_as_float(hv.y << 16), acc[2]);
    acc[3] = fmaf(ex, __uint_as_float(hv.y & 0xFFFF0000u), acc[3]);
    acc[4] = fmaf(ex, __uint_as_float(hv.z << 16), acc[4]);
    acc[5] = fmaf(ex, __uint_as_float(hv.z & 0xFFFF0000u), acc[5]);
    acc[6] = fmaf(ex, __uint_as_float(hv.w << 16), acc[6]);
    acc[7] = fmaf(ex, __uint_as_float(hv.w & 0xFFFF0000u), acc[7]);
}

__global__ __launch_bounds__(256) void gat_gather(
    const unsigned short* __restrict__ hb,
    const float* __restrict__ as_, const float* __restrict__ ad_,
    const int* __restrict__ offsets, const unsigned short* __restrict__ srcs,
    const int* __restrict__ perm,
    const float* __restrict__ bvec, const float* __restrict__ x0,
    float* __restrict__ xout, int N) {
    int wid = (blockIdx.x * blockDim.x + threadIdx.x) >> 6;  // global wave id
    int lane = threadIdx.x & 63;
    int g = lane >> 3;       // node slot 0..7
    int q = lane & 7;        // feature octet 0..7
    int ni = wid * 8 + g;
    bool active = ni < N;
    int node = active ? perm[ni] : 0;
    int beg = active ? offsets[node] : 0;
    int end = active ? offsets[node + 1] : 0;
    int deg = end - beg;
    float adv = active ? ad_[node] : 0.f;
    // group-max degree (uniform loop bound); g lives in lane bits 3..5
    int mx = deg;
    mx = max(mx, __shfl_xor(mx, 8, 64));
    mx = max(mx, __shfl_xor(mx, 16, 64));
    mx = max(mx, __shfl_xor(mx, 32, 64));

    float acc[8];
#pragma unroll
    for (int k = 0; k < 8; k++) acc[k] = 0.f;
    float denom = 0.f;
    const unsigned short* hq = hb + (q << 3);   // + q*8 shorts (16B)

#define LRELU_EXP(E_) __expf((E_) > 0.f ? (E_) : NEG_SLOPE * (E_))

    int p0 = (int)srcs[(0 < deg) ? beg + 0 : 0];
    int p1 = (int)srcs[(1 < deg) ? beg + 1 : 0];
    int p2 = (int)srcs[(2 < deg) ? beg + 2 : 0];
    int p3 = (int)srcs[(3 < deg) ? beg + 3 : 0];

    for (int st = 0; st < mx; st += 4) {
        int ns = st + 4;
        int n0 = (int)srcs[(ns + 0 < deg) ? beg + ns + 0 : 0];
        int n1 = (int)srcs[(ns + 1 < deg) ? beg + ns + 1 : 0];
        int n2 = (int)srcs[(ns + 2 < deg) ? beg + ns + 2 : 0];
        int n3 = (int)srcs[(ns + 3 < deg) ? beg + ns + 3 : 0];
        uint4 hv0 = *(const uint4*)(hq + ((size_t)p0 << 6));
        uint4 hv1 = *(const uint4*)(hq + ((size_t)p1 << 6));
        uint4 hv2 = *(const uint4*)(hq + ((size_t)p2 << 6));
        uint4 hv3 = *(const uint4*)(hq + ((size_t)p3 << 6));
        float e0 = as_[p0] + adv;
        float e1 = as_[p1] + adv;
        float e2 = as_[p2] + adv;
        float e3 = as_[p3] + adv;
        float ex0 = (st + 0 < deg) ? LRELU_EXP(e0) : 0.f;
        float ex1 = (st + 1 < deg) ? LRELU_EXP(e1) : 0.f;
        float ex2 = (st + 2 < deg) ? LRELU_EXP(e2) : 0.f;
        float ex3 = (st + 3 < deg) ? LRELU_EXP(e3) : 0.f;
        denom += (ex0 + ex1) + (ex2 + ex3);
        fma8(acc, ex0, hv0);
        fma8(acc, ex1, hv1);
        fma8(acc, ex2, hv2);
        fma8(acc, ex3, hv3);
        p0 = n0; p1 = n1; p2 = n2; p3 = n3;
    }
#undef LRELU_EXP

    if (active) {
        float inv = denom > 0.f ? 1.f / denom : 0.f;
        int fb = q * 8;
        f32x4 b0 = *(const f32x4*)(bvec + fb);
        f32x4 b1 = *(const f32x4*)(bvec + fb + 4);
        const float* x0r = x0 + (size_t)node * FDIM + fb;
        f32x4 x0a = *(const f32x4*)(x0r);
        f32x4 x0b = *(const f32x4*)(x0r + 4);
        f32x4 o0, o1;
        o0.x = BETA * (acc[0] * inv + b0.x) + (1.f - BETA) * x0a.x;
        o0.y = BETA * (acc[1] * inv + b0.y) + (1.f - BETA) * x0a.y;
        o0.z = BETA * (acc[2] * inv + b0.z) + (1.f - BETA) * x0a.z;
        o0.w = BETA * (acc[3] * inv + b0.w) + (1.f - BETA) * x0a.w;
        o1.x = BETA * (acc[4] * inv + b1.x) + (1.f - BETA) * x0b.x;
        o1.y = BETA * (acc[5] * inv + b1.y) + (1.f - BETA) * x0b.y;
        o1.z = BETA * (acc[6] * inv + b1.z) + (1.f - BETA) * x0b.z;
        o1.w = BETA * (acc[7] * inv + b1.w) + (1.f - BETA) * x0b.w;
        float* xr = xout + (size_t)node * FDIM + fb;
        *(f32x4*)(xr) = o0;
        *(f32x4*)(xr + 4) = o1;
    }
}

// ---------------------------------------------------------------------------
extern "C" void kernel_launch(void* const* d_in, const int* in_sizes, int n_in,
                              void* d_out, int out_size, void* d_ws, size_t ws_size,
                              hipStream_t stream) {
    const int N = N_NODES;
    const int E = in_sizes[1] / 2;
    const int NB = (N + 255) >> 8;   // 196 buckets
    const int CAP = (((E / N) * 256) * 2 + 1023) & ~1023;   // 16384 here

    const float* x     = (const float*)d_in[0];
    const void*  ei    = d_in[1];
    const float* W     = (const float*)d_in[2];
    const float* a_src = (const float*)d_in[3];
    const float* a_dst = (const float*)d_in[4];
    const float* bvec  = (const float*)d_in[5];
    const float* fc_w  = (const float*)d_in[6];
    const float* fc_b  = (const float*)d_in[7];

    float* out = (float*)d_out;                 // [N, F]
    float* x3  = out + (size_t)N * FDIM;        // [N, F] (second output = h)

    char* p = (char*)d_ws;
    auto alloc = [&](size_t bytes) -> void* {
        void* r = (void*)p;
        p += (bytes + 255) & ~(size_t)255;
        return r;
    };
    int*            gCursor  = (int*)alloc(768 * 4);   // gCursor + degCnt + cursorRel
    unsigned int*   pairs    = (unsigned int*)alloc((size_t)256 * CAP * 4);
    unsigned short* srcs     = (unsigned short*)alloc((size_t)E * 2);
    int*            offsets  = (int*)alloc((size_t)(N + 1) * 4);
    int*            perm     = (int*)alloc((size_t)N * 4);
    float*          as_      = (float*)alloc((size_t)N * 4);
    float*          ad_      = (float*)alloc((size_t)N * 4);
    unsigned short* hbuf     = (unsigned short*)alloc((size_t)N * FDIM * 2);
    float*          xbuf     = (float*)alloc((size_t)N * FDIM * 4);
    unsigned short* WTh      = (unsigned short*)alloc(4096 * 2);
    unsigned short* WTl      = (unsigned short*)alloc(4096 * 2);
    unsigned short* FTh      = (unsigned short*)alloc(4096 * 2);
    unsigned short* FTl      = (unsigned short*)alloc(4096 * 2);
    int* degCnt    = gCursor + 256;
    int* cursorRel = gCursor + 512;

    hipMemsetAsync(gCursor, 0, 768 * 4, stream);

    const int nChunks = (E + CHUNK - 1) / CHUNK;
    scatter_pairs<<<nChunks + 1, 256, 0, stream>>>(
        (const unsigned int*)ei, gCursor, pairs, E, CAP, nChunks,
        W, fc_w, WTh, WTl, FTh, FTl);
    bucket_sort<<<NB, 1024, 0, stream>>>(pairs, gCursor, offsets, srcs, degCnt, N, E, CAP);
    deg_scatter<<<(N + DCHUNK - 1) / DCHUNK, 256, 0, stream>>>(
        offsets, degCnt, cursorRel, perm, N);

    int tgrid = (N + 63) / 64;
    int gwaves = (N + 7) / 8;
    int ggrid = (gwaves + 3) / 4;   // 4 waves (256 thr) per block

    // layer 1
    transform_k<<<tgrid, 256, 0, stream>>>(x, WTh, WTl, a_src, a_dst, nullptr,
                                           hbuf, nullptr, as_, ad_, N);
    gat_gather<<<ggrid, 256, 0, stream>>>(hbuf, as_, ad_, offsets, srcs, perm,
                                          bvec, x, xbuf, N);
    // layer 2
    transform_k<<<tgrid, 256, 0, stream>>>(xbuf, WTh, WTl, a_src, a_dst, nullptr,
                                           hbuf, nullptr, as_, ad_, N);
    gat_gather<<<ggrid, 256, 0, stream>>>(hbuf, as_, ad_, offsets, srcs, perm,
                                          bvec, x, xbuf, N);
    // layer 3
    transform_k<<<tgrid, 256, 0, stream>>>(xbuf, WTh, WTl, a_src, a_dst, nullptr,
                                           hbuf, nullptr, as_, ad_, N);
    gat_gather<<<ggrid, 256, 0, stream>>>(hbuf, as_, ad_, offsets, srcs, perm,
                                          bvec, x, x3, N);
    // final fc: out = x3 @ fc_w + fc_b
    transform_k<<<tgrid, 256, 0, stream>>>(x3, FTh, FTl, nullptr, nullptr, fc_b,
                                           nullptr, out, nullptr, nullptr, N);
}